// Round 6
// baseline (888.399 us; speedup 1.0000x reference)
//
#include <hip/hip_runtime.h>
#include <hip/hip_bf16.h>

#define DEVINL __device__ __forceinline__

constexpr int NN   = 100000;
constexpr int NE   = 1600000;
constexpr int DIN  = 256;
constexpr int DH   = 128;
constexpr int DOUT = 64;
constexpr float BN_EPS = 1e-5f;
constexpr int NBUCK = (NN + 127) / 128;          // 782 buckets of 128 dst nodes
constexpr int CHUNK = 8192;                      // edges per k_bfill block
constexpr int NBF   = (NE + CHUNK - 1) / CHUNK;  // 196
constexpr int SORT_CAP = 4096;                   // max edges per bucket (mean 2046, std 45)

typedef __attribute__((ext_vector_type(8))) short short8;
typedef __attribute__((ext_vector_type(4))) float f32x4;

DEVINL ushort f2bf(float f) {
  uint u = __builtin_bit_cast(uint, f);
  u += 0x7FFFu + ((u >> 16) & 1u);
  return (ushort)(u >> 16);
}
DEVINL float bf2f(ushort u) {
  return __builtin_bit_cast(float, ((uint)u) << 16);
}

// ---------------- bucket-CSR build ----------------

__launch_bounds__(256)
__global__ void k_bhist(const int* __restrict__ dst, int* __restrict__ bcnt) {
  __shared__ int h[NBUCK];
  const int t = threadIdx.x;
  for (int i = t; i < NBUCK; i += 256) h[i] = 0;
  __syncthreads();
  const int e00 = blockIdx.x * 4096;
  for (int k = 0; k < 16; ++k) {
    int e = e00 + k * 256 + t;
    if (e < NE) atomicAdd(&h[dst[e] >> 7], 1);
  }
  __syncthreads();
  for (int i = t; i < NBUCK; i += 256)
    if (h[i]) atomicAdd(&bcnt[i], h[i]);
}

__global__ void k_bscan(const int* __restrict__ bcnt, int* __restrict__ boffs,
                        int* __restrict__ gcursor) {
  __shared__ int s[1024];
  const int t = threadIdx.x;
  int v = (t < NBUCK) ? bcnt[t] : 0;
  int x = v;
  s[t] = x; __syncthreads();
  for (int off = 1; off < 1024; off <<= 1) {
    int y = (t >= off) ? s[t - off] : 0;
    __syncthreads();
    x += y; s[t] = x;
    __syncthreads();
  }
  if (t < NBUCK) { boffs[t] = x - v; gcursor[t] = x - v; }
  if (t == 0) boffs[NBUCK] = NE;
}

// block-binned scatter: chunk -> LDS-sorted by bucket -> grouped global writes
__launch_bounds__(256)
__global__ void k_bfill(const int* __restrict__ src, const int* __restrict__ dst,
                        int* __restrict__ gcursor, uint* __restrict__ ebuf) {
  __shared__ uint   sortv[CHUNK];   // 32 KB
  __shared__ ushort sortb[CHUNK];   // 16 KB
  __shared__ int hist[NBUCK];
  __shared__ int start[NBUCK];
  __shared__ int gbase[NBUCK];
  const int t = threadIdx.x;
  const int e00 = blockIdx.x * CHUNK;
  const int nv = min(CHUNK, NE - e00);

  for (int i = t; i < NBUCK; i += 256) hist[i] = 0;
  __syncthreads();
  for (int k = 0; k < CHUNK / 256; ++k) {
    int e = e00 + k * 256 + t;
    if (e < NE) atomicAdd(&hist[dst[e] >> 7], 1);
  }
  __syncthreads();

  // exclusive scan of hist -> start (thread t owns buckets [4t,4t+4))
  int c[4]; int sl = 0;
#pragma unroll
  for (int j = 0; j < 4; ++j) {
    int b = t * 4 + j;
    c[j] = (b < NBUCK) ? hist[b] : 0;
    sl += c[j];
  }
  gbase[t] = sl;                       // reuse gbase[0..255] as scan temp
  __syncthreads();
  int x = sl;
  for (int off = 1; off < 256; off <<= 1) {
    int y = (t >= off) ? gbase[t - off] : 0;
    __syncthreads();
    x += y; gbase[t] = x;
    __syncthreads();
  }
  int run = x - sl;                    // exclusive prefix
#pragma unroll
  for (int j = 0; j < 4; ++j) {
    int b = t * 4 + j;
    if (b < NBUCK) start[b] = run;
    run += c[j];
  }
  __syncthreads();

  // reserve global space per bucket; hist becomes the local cursor
  for (int i = t; i < NBUCK; i += 256) {
    int cnt = hist[i];
    if (cnt > 0) gbase[i] = atomicAdd(&gcursor[i], cnt);
    hist[i] = start[i];
  }
  __syncthreads();

  // local bin into LDS
  for (int k = 0; k < CHUNK / 256; ++k) {
    int e = e00 + k * 256 + t;
    if (e < NE) {
      int d = dst[e];
      int b = d >> 7;
      int r = atomicAdd(&hist[b], 1);
      sortv[r] = (uint)src[e] | ((uint)(d & 127) << 17);
      sortb[r] = (ushort)b;
    }
  }
  __syncthreads();

  // grouped write-out
  for (int i = t; i < nv; i += 256) {
    int b = sortb[i];
    ebuf[gbase[b] + (i - start[b])] = sortv[i];
  }
}

// per-bucket counting sort (in place): bucket-grouped packed edges -> fully
// dst-sorted plain-src ints; emits per-node offs and dinv.
__launch_bounds__(256)
__global__ void k_sort(uint* __restrict__ ebuf, const int* __restrict__ boffs,
                       int* __restrict__ offs, float* __restrict__ dinv) {
  __shared__ uint vals[SORT_CAP];
  __shared__ int cnt[128], pre[128], cur[128];
  const int t = threadIdx.x;
  const int b = blockIdx.x;
  const int e0 = boffs[b];
  const int e1 = boffs[b + 1];
  const int n = e1 - e0;

  if (t < 128) cnt[t] = 0;
  __syncthreads();
  for (int i = t; i < n; i += 256) {
    uint v = ebuf[e0 + i];
    vals[i] = v;
    atomicAdd(&cnt[v >> 17], 1);
  }
  __syncthreads();

  // exclusive scan of 128 counters
  if (t < 128) pre[t] = cnt[t];
  __syncthreads();
  for (int off = 1; off < 128; off <<= 1) {
    int y = (t < 128 && t >= off) ? pre[t - off] : 0;
    __syncthreads();
    if (t < 128) pre[t] += y;
    __syncthreads();
  }
  if (t < 128) {
    const int excl = pre[t] - cnt[t];
    cur[t] = excl;
    const int nid = b * 128 + t;
    if (nid < NN) {
      offs[nid] = e0 + excl;
      dinv[nid] = rsqrtf((float)cnt[t] + 1.0f);   // +1 self loop
    } else if (nid == NN) {
      offs[NN] = e0 + excl;                       // == NE
    }
  }
  __syncthreads();

  // scatter back in place, sorted by local dst, payload = plain src
  for (int i = t; i < n; i += 256) {
    const uint v = vals[i];
    const int r = atomicAdd(&cur[v >> 17], 1);
    ebuf[e0 + r] = v & 0x1FFFFu;
  }
}

// ---------------- weight pack (fragment layout) ----------------
__global__ void k_pack(const float* __restrict__ W, ushort* __restrict__ Wp, int K, int Nw) {
  int t = blockIdx.x * 256 + threadIdx.x;
  int total = (K / 32) * (Nw / 16) * 64;
  if (t >= total) return;
  int l  = t & 63;
  int nf = (t >> 6) % (Nw / 16);
  int ks = (t >> 6) / (Nw / 16);
  int krow = ks * 32 + (l >> 4) * 8;
  int col  = nf * 16 + (l & 15);
  ushort out[8];
#pragma unroll
  for (int j = 0; j < 8; ++j) out[j] = f2bf(W[(size_t)(krow + j) * Nw + col]);
  *(uint4*)&Wp[(size_t)t * 8] = *(const uint4*)out;
}

// ---------------- GEMM: C[M,NW] = bf16( (bnrelu(A[M,K]) @ W) * dinv[row] ) ----------------
template <int K, int NW, bool BN>
__launch_bounds__(256)
__global__ void k_gemm(const float* __restrict__ A, const ushort* __restrict__ Wp,
                       const float* __restrict__ scale, const float* __restrict__ shift,
                       const float* __restrict__ dinv, ushort* __restrict__ Cout, int M) {
  constexpr int LDA = 40;
  __shared__ ushort lds[128 * LDA];
  const int t = threadIdx.x;
  const int lane = t & 63;
  const int wid = t >> 6;
  const int m0 = blockIdx.x * 128;

  constexpr int WAVES_N = (NW == 128) ? 2 : 1;
  constexpr int MF  = (NW == 128) ? 4 : 2;
  constexpr int NFW = 4;
  constexpr int NFT = NW / 16;
  const int wr = wid / WAVES_N;
  const int wc = wid % WAVES_N;
  const int mbase = wr * (MF * 16);
  const int nfg0 = wc * NFW;

  f32x4 acc[MF][NFW] = {};

  const int cg = t & 7;
  const int r0 = t >> 3;

  const int nkt = K / 32;
  for (int kt = 0; kt < nkt; ++kt) {
    const int k0 = kt * 32;
    float4 s4 = {1.f, 1.f, 1.f, 1.f}, h4 = {0.f, 0.f, 0.f, 0.f};
    if (BN) {
      s4 = *(const float4*)&scale[k0 + cg * 4];
      h4 = *(const float4*)&shift[k0 + cg * 4];
    }
    __syncthreads();
#pragma unroll
    for (int p = 0; p < 4; ++p) {
      const int row = p * 32 + r0;
      const int grow = m0 + row;
      float4 v = {0.f, 0.f, 0.f, 0.f};
      if (grow < M) v = *(const float4*)&A[(size_t)grow * K + k0 + cg * 4];
      if (BN) {
        v.x = fmaxf(v.x * s4.x + h4.x, 0.f);
        v.y = fmaxf(v.y * s4.y + h4.y, 0.f);
        v.z = fmaxf(v.z * s4.z + h4.z, 0.f);
        v.w = fmaxf(v.w * s4.w + h4.w, 0.f);
      }
      ushort4 w;
      w.x = f2bf(v.x); w.y = f2bf(v.y); w.z = f2bf(v.z); w.w = f2bf(v.w);
      *(ushort4*)&lds[row * LDA + cg * 4] = w;
    }
    __syncthreads();

    short8 bfrag[NFW];
#pragma unroll
    for (int nf = 0; nf < NFW; ++nf) {
      const size_t bidx = ((size_t)(kt * NFT + nfg0 + nf) * 64 + lane) * 8;
      bfrag[nf] = *(const short8*)&Wp[bidx];
    }
#pragma unroll
    for (int mf = 0; mf < MF; ++mf) {
      const short8 af =
          *(const short8*)&lds[(mbase + mf * 16 + (lane & 15)) * LDA + ((lane >> 4) * 8)];
#pragma unroll
      for (int nf = 0; nf < NFW; ++nf)
        acc[mf][nf] = __builtin_amdgcn_mfma_f32_16x16x32_bf16(af, bfrag[nf], acc[mf][nf], 0, 0, 0);
    }
  }

#pragma unroll
  for (int mf = 0; mf < MF; ++mf) {
#pragma unroll
    for (int r = 0; r < 4; ++r) {
      const int grow = m0 + mbase + mf * 16 + (lane >> 4) * 4 + r;
      if (grow < M) {
        const float dv = dinv[grow];
#pragma unroll
        for (int nf = 0; nf < NFW; ++nf) {
          const int gcol = (nfg0 + nf) * 16 + (lane & 15);
          Cout[(size_t)grow * NW + gcol] = f2bf(acc[mf][nf][r] * dv);
        }
      }
    }
  }
}

// ---------------- pull-propagate (wave per node, pair-gather) ----------------
// G pre-scaled by dinv[src].  H[d] = dinv[d]*( sum_{s->d} G'[s] + G'[d] ) + b
// Two 32-lane halves gather different edges' rows (ushort4 = 8B/lane, 256B/row).
// Optionally fuses BN sum/sumsq accumulation (grid-stride, block-level reduce).
template <bool STATS>
__launch_bounds__(256)
__global__ void k_prop128(const ushort* __restrict__ G, const int* __restrict__ offs,
                          const int* __restrict__ csr, const float* __restrict__ dinv,
                          const float* __restrict__ bias, float* __restrict__ H,
                          float* __restrict__ gsum, float* __restrict__ gsumsq) {
  const int t = threadIdx.x;
  const int wid = t >> 6;
  const int lane = t & 63;
  const int h = lane >> 5;     // half: which edge of the pair
  const int li = lane & 31;
  const int f0 = li * 4;       // 4 features per lane

  float s0 = 0.f, s1 = 0.f, s2 = 0.f, s3 = 0.f;   // stats: sum
  float q0 = 0.f, q1 = 0.f, q2 = 0.f, q3 = 0.f;   // stats: sumsq

  const int stride = gridDim.x * 4;
  for (int nid = blockIdx.x * 4 + wid; nid < NN; nid += stride) {
    float a0 = 0.f, a1 = 0.f, a2 = 0.f, a3 = 0.f;
    if (h == 0) {   // self term only once
      ushort4 gs = *(const ushort4*)&G[(size_t)nid * 128 + f0];
      a0 = bf2f(gs.x); a1 = bf2f(gs.y); a2 = bf2f(gs.z); a3 = bf2f(gs.w);
    }
    const int e0 = offs[nid];
    const int e1 = offs[nid + 1];
    for (int e = e0; e < e1; e += 16) {
      int idx[8];
#pragma unroll
      for (int j = 0; j < 8; ++j) {
        const int ei = e + 2 * j + h;
        idx[j] = (ei < e1) ? csr[ei] : nid;
      }
      ushort4 g[8];
#pragma unroll
      for (int j = 0; j < 8; ++j)
        g[j] = *(const ushort4*)&G[(size_t)idx[j] * 128 + f0];
#pragma unroll
      for (int j = 0; j < 8; ++j) {
        const int ei = e + 2 * j + h;
        if (ei < e1) {
          a0 += bf2f(g[j].x); a1 += bf2f(g[j].y);
          a2 += bf2f(g[j].z); a3 += bf2f(g[j].w);
        }
      }
    }
    // combine the two halves
    a0 += __shfl_xor(a0, 32, 64);
    a1 += __shfl_xor(a1, 32, 64);
    a2 += __shfl_xor(a2, 32, 64);
    a3 += __shfl_xor(a3, 32, 64);
    if (h == 0) {
      const float di = dinv[nid];
      const float4 b4 = *(const float4*)&bias[f0];
      float4 o;
      o.x = a0 * di + b4.x; o.y = a1 * di + b4.y;
      o.z = a2 * di + b4.z; o.w = a3 * di + b4.w;
      *(float4*)&H[(size_t)nid * 128 + f0] = o;
      if (STATS) {
        s0 += o.x; s1 += o.y; s2 += o.z; s3 += o.w;
        q0 += o.x * o.x; q1 += o.y * o.y; q2 += o.z * o.z; q3 += o.w * o.w;
      }
    }
  }

  if (STATS) {
    __shared__ float ls[4][32][4];
    __shared__ float lq[4][32][4];
    if (h == 0) {
      ls[wid][li][0] = s0; ls[wid][li][1] = s1; ls[wid][li][2] = s2; ls[wid][li][3] = s3;
      lq[wid][li][0] = q0; lq[wid][li][1] = q1; lq[wid][li][2] = q2; lq[wid][li][3] = q3;
    }
    __syncthreads();
    if (t < 32) {
#pragma unroll
      for (int k = 0; k < 4; ++k) {
        float v = ls[0][t][k] + ls[1][t][k] + ls[2][t][k] + ls[3][t][k];
        atomicAdd(&gsum[t * 4 + k], v);
      }
    } else if (t < 64) {
      const int u = t - 32;
#pragma unroll
      for (int k = 0; k < 4; ++k) {
        float v = lq[0][u][k] + lq[1][u][k] + lq[2][u][k] + lq[3][u][k];
        atomicAdd(&gsumsq[u * 4 + k], v);
      }
    }
  }
}

// quad-gather: four 16-lane groups each gather a different edge's 128B row
__launch_bounds__(256)
__global__ void k_prop64(const ushort* __restrict__ G, const int* __restrict__ offs,
                         const int* __restrict__ csr, const float* __restrict__ dinv,
                         const float* __restrict__ bias, float* __restrict__ out, int n) {
  const int wid = threadIdx.x >> 6;
  const int lane = threadIdx.x & 63;
  const int nid = blockIdx.x * 4 + wid;
  if (nid >= n) return;
  const int q = lane >> 4;
  const int li = lane & 15;
  const int f0 = li * 4;

  float a0 = 0.f, a1 = 0.f, a2 = 0.f, a3 = 0.f;
  if (q == 0) {   // self term
    ushort4 gs = *(const ushort4*)&G[(size_t)nid * 64 + f0];
    a0 = bf2f(gs.x); a1 = bf2f(gs.y); a2 = bf2f(gs.z); a3 = bf2f(gs.w);
  }
  const int e0 = offs[nid];
  const int e1 = offs[nid + 1];
  for (int e = e0; e < e1; e += 16) {
    int idx[4];
#pragma unroll
    for (int j = 0; j < 4; ++j) {
      const int ei = e + 4 * j + q;
      idx[j] = (ei < e1) ? csr[ei] : nid;
    }
    ushort4 g[4];
#pragma unroll
    for (int j = 0; j < 4; ++j)
      g[j] = *(const ushort4*)&G[(size_t)idx[j] * 64 + f0];
#pragma unroll
    for (int j = 0; j < 4; ++j) {
      const int ei = e + 4 * j + q;
      if (ei < e1) {
        a0 += bf2f(g[j].x); a1 += bf2f(g[j].y);
        a2 += bf2f(g[j].z); a3 += bf2f(g[j].w);
      }
    }
  }
  // reduce across the 4 groups
  a0 += __shfl_xor(a0, 16, 64); a1 += __shfl_xor(a1, 16, 64);
  a2 += __shfl_xor(a2, 16, 64); a3 += __shfl_xor(a3, 16, 64);
  a0 += __shfl_xor(a0, 32, 64); a1 += __shfl_xor(a1, 32, 64);
  a2 += __shfl_xor(a2, 32, 64); a3 += __shfl_xor(a3, 32, 64);
  if (lane < 16) {
    const float di = dinv[nid];
    const float4 b4 = *(const float4*)&bias[f0];
    float4 o;
    o.x = a0 * di + b4.x; o.y = a1 * di + b4.y;
    o.z = a2 * di + b4.z; o.w = a3 * di + b4.w;
    *(float4*)&out[(size_t)nid * 64 + f0] = o;
  }
}

__global__ void k_finalize(const float* __restrict__ sum, const float* __restrict__ sumsq,
                           const float* __restrict__ g, const float* __restrict__ bt,
                           float* __restrict__ scale, float* __restrict__ shift) {
  const int d = threadIdx.x;
  const float inv_n = 1.0f / (float)NN;
  const float mu = sum[d] * inv_n;
  float var = sumsq[d] * inv_n - mu * mu;
  const float rs = rsqrtf(var + BN_EPS);
  const float sc = g[d] * rs;
  scale[d] = sc;
  shift[d] = bt[d] - mu * sc;
}

// ---------------- launch ----------------
extern "C" void kernel_launch(void* const* d_in, const int* in_sizes, int n_in,
                              void* d_out, int out_size, void* d_ws, size_t ws_size,
                              hipStream_t stream) {
  const float* x   = (const float*)d_in[0];
  const int*  ei   = (const int*)d_in[1];
  const int*  srcp = ei;
  const int*  dstp = ei + NE;
  const float* W1  = (const float*)d_in[2];
  const float* b1  = (const float*)d_in[3];
  const float* g1  = (const float*)d_in[4];
  const float* bt1 = (const float*)d_in[5];
  const float* W2  = (const float*)d_in[6];
  const float* b2  = (const float*)d_in[7];
  const float* g2  = (const float*)d_in[8];
  const float* bt2 = (const float*)d_in[9];
  const float* W3  = (const float*)d_in[10];
  const float* b3  = (const float*)d_in[11];
  float* out = (float*)d_out;

  char* p = (char*)d_ws;
  auto alloc = [&](size_t bytes) {
    char* r = p;
    p += (bytes + 255) & ~(size_t)255;
    return r;
  };
  int*    bcnt    = (int*)alloc(NBUCK * 4);
  int*    boffs   = (int*)alloc((NBUCK + 1) * 4);
  int*    gcursor = (int*)alloc(NBUCK * 4);
  uint*   ebuf    = (uint*)alloc((size_t)NE * 4);   // packed, then sorted plain-src
  int*    offs    = (int*)alloc((NN + 1) * 4);
  float*  dinv    = (float*)alloc(NN * 4);
  float*  gsum    = (float*)alloc(DH * 4);
  float*  gsumsq  = (float*)alloc(DH * 4);
  float*  scale   = (float*)alloc(DH * 4);
  float*  shift   = (float*)alloc(DH * 4);
  ushort* Wp1     = (ushort*)alloc((size_t)DIN * DH * 2);
  ushort* Wp2     = (ushort*)alloc((size_t)DH * DH * 2);
  ushort* Wp3     = (ushort*)alloc((size_t)DH * DOUT * 2);
  ushort* G       = (ushort*)alloc((size_t)NN * DH * 2);
  float*  H       = (float*)alloc((size_t)NN * DH * 4);

  const int GB = (NN + 127) / 128;   // 782 gemm blocks
  const int PB = (NN + 3) / 4;       // 25000 prop64 blocks
  const int SB = 2048;               // stats-fused prop128 blocks (32 waves/CU)

  // bucket-CSR build + per-bucket sort -> per-node CSR
  hipMemsetAsync(bcnt, 0, NBUCK * 4, stream);
  k_bhist<<<(NE + 4095) / 4096, 256, 0, stream>>>(dstp, bcnt);
  k_bscan<<<1, 1024, 0, stream>>>(bcnt, boffs, gcursor);
  k_bfill<<<NBF, 256, 0, stream>>>(srcp, dstp, gcursor, ebuf);
  k_sort<<<NBUCK, 256, 0, stream>>>(ebuf, boffs, offs, dinv);
  const int* csr = (const int*)ebuf;

  // weight packing
  k_pack<<<16, 256, 0, stream>>>(W1, Wp1, DIN, DH);
  k_pack<<<8, 256, 0, stream>>>(W2, Wp2, DH, DH);
  k_pack<<<4, 256, 0, stream>>>(W3, Wp3, DH, DOUT);

  // layer 1
  k_gemm<DIN, DH, false><<<GB, 256, 0, stream>>>(x, Wp1, nullptr, nullptr, dinv, G, NN);
  hipMemsetAsync(gsum, 0, DH * 4, stream);
  hipMemsetAsync(gsumsq, 0, DH * 4, stream);
  k_prop128<true><<<SB, 256, 0, stream>>>(G, offs, csr, dinv, b1, H, gsum, gsumsq);
  k_finalize<<<1, DH, 0, stream>>>(gsum, gsumsq, g1, bt1, scale, shift);

  // layer 2
  k_gemm<DH, DH, true><<<GB, 256, 0, stream>>>(H, Wp2, scale, shift, dinv, G, NN);
  hipMemsetAsync(gsum, 0, DH * 4, stream);
  hipMemsetAsync(gsumsq, 0, DH * 4, stream);
  k_prop128<true><<<SB, 256, 0, stream>>>(G, offs, csr, dinv, b2, H, gsum, gsumsq);
  k_finalize<<<1, DH, 0, stream>>>(gsum, gsumsq, g2, bt2, scale, shift);

  // layer 3
  k_gemm<DH, DOUT, true><<<GB, 256, 0, stream>>>(H, Wp3, scale, shift, dinv, G, NN);
  k_prop64<<<PB, 256, 0, stream>>>(G, offs, csr, dinv, b3, out, NN);
}

// Round 9
// 598.353 us; speedup vs baseline: 1.4847x; 1.4847x over previous
//
#include <hip/hip_runtime.h>
#include <hip/hip_bf16.h>

#define DEVINL __device__ __forceinline__

constexpr int NN   = 100000;
constexpr int NE   = 1600000;
constexpr int DIN  = 256;
constexpr int DH   = 128;
constexpr int DOUT = 64;
constexpr float BN_EPS = 1e-5f;
constexpr int NBUCK = (NN + 127) / 128;          // 782 buckets of 128 dst nodes
constexpr int CHUNK = 8192;                      // edges per k_bfill block
constexpr int NBF   = (NE + CHUNK - 1) / CHUNK;  // 196
constexpr int SORT_CAP = 4096;                   // max edges per bucket (mean 2046, std 45)

typedef __attribute__((ext_vector_type(8))) short short8;
typedef __attribute__((ext_vector_type(4))) float f32x4;

DEVINL ushort f2bf(float f) {
  uint u = __builtin_bit_cast(uint, f);
  u += 0x7FFFu + ((u >> 16) & 1u);
  return (ushort)(u >> 16);
}
DEVINL float bf2f(ushort u) {
  return __builtin_bit_cast(float, ((uint)u) << 16);
}

// ---------------- bucket-CSR build ----------------

__launch_bounds__(256)
__global__ void k_bhist(const int* __restrict__ dst, int* __restrict__ bcnt) {
  __shared__ int h[NBUCK];
  const int t = threadIdx.x;
  for (int i = t; i < NBUCK; i += 256) h[i] = 0;
  __syncthreads();
  const int e00 = blockIdx.x * 4096;
  for (int k = 0; k < 16; ++k) {
    int e = e00 + k * 256 + t;
    if (e < NE) atomicAdd(&h[dst[e] >> 7], 1);
  }
  __syncthreads();
  for (int i = t; i < NBUCK; i += 256)
    if (h[i]) atomicAdd(&bcnt[i], h[i]);
}

__global__ void k_bscan(const int* __restrict__ bcnt, int* __restrict__ boffs,
                        int* __restrict__ gcursor) {
  __shared__ int s[1024];
  const int t = threadIdx.x;
  int v = (t < NBUCK) ? bcnt[t] : 0;
  int x = v;
  s[t] = x; __syncthreads();
  for (int off = 1; off < 1024; off <<= 1) {
    int y = (t >= off) ? s[t - off] : 0;
    __syncthreads();
    x += y; s[t] = x;
    __syncthreads();
  }
  if (t < NBUCK) { boffs[t] = x - v; gcursor[t] = x - v; }
  if (t == 0) boffs[NBUCK] = NE;
}

// block-binned scatter: chunk -> LDS-sorted by bucket -> grouped global writes
__launch_bounds__(256)
__global__ void k_bfill(const int* __restrict__ src, const int* __restrict__ dst,
                        int* __restrict__ gcursor, uint* __restrict__ ebuf) {
  __shared__ uint   sortv[CHUNK];   // 32 KB
  __shared__ ushort sortb[CHUNK];   // 16 KB
  __shared__ int hist[NBUCK];
  __shared__ int start[NBUCK];
  __shared__ int gbase[NBUCK];
  const int t = threadIdx.x;
  const int e00 = blockIdx.x * CHUNK;
  const int nv = min(CHUNK, NE - e00);

  for (int i = t; i < NBUCK; i += 256) hist[i] = 0;
  __syncthreads();
  for (int k = 0; k < CHUNK / 256; ++k) {
    int e = e00 + k * 256 + t;
    if (e < NE) atomicAdd(&hist[dst[e] >> 7], 1);
  }
  __syncthreads();

  // exclusive scan of hist -> start (thread t owns buckets [4t,4t+4))
  int c[4]; int sl = 0;
#pragma unroll
  for (int j = 0; j < 4; ++j) {
    int b = t * 4 + j;
    c[j] = (b < NBUCK) ? hist[b] : 0;
    sl += c[j];
  }
  gbase[t] = sl;                       // reuse gbase[0..255] as scan temp
  __syncthreads();
  int x = sl;
  for (int off = 1; off < 256; off <<= 1) {
    int y = (t >= off) ? gbase[t - off] : 0;
    __syncthreads();
    x += y; gbase[t] = x;
    __syncthreads();
  }
  int run = x - sl;                    // exclusive prefix
#pragma unroll
  for (int j = 0; j < 4; ++j) {
    int b = t * 4 + j;
    if (b < NBUCK) start[b] = run;
    run += c[j];
  }
  __syncthreads();

  // reserve global space per bucket; hist becomes the local cursor
  for (int i = t; i < NBUCK; i += 256) {
    int cnt = hist[i];
    if (cnt > 0) gbase[i] = atomicAdd(&gcursor[i], cnt);
    hist[i] = start[i];
  }
  __syncthreads();

  // local bin into LDS
  for (int k = 0; k < CHUNK / 256; ++k) {
    int e = e00 + k * 256 + t;
    if (e < NE) {
      int d = dst[e];
      int b = d >> 7;
      int r = atomicAdd(&hist[b], 1);
      sortv[r] = (uint)src[e] | ((uint)(d & 127) << 17);
      sortb[r] = (ushort)b;
    }
  }
  __syncthreads();

  // grouped write-out
  for (int i = t; i < nv; i += 256) {
    int b = sortb[i];
    ebuf[gbase[b] + (i - start[b])] = sortv[i];
  }
}

// per-bucket counting sort (in place): bucket-grouped packed edges -> fully
// dst-sorted plain-src ints; emits per-node offs and dinv.
__launch_bounds__(256)
__global__ void k_sort(uint* __restrict__ ebuf, const int* __restrict__ boffs,
                       int* __restrict__ offs, float* __restrict__ dinv) {
  __shared__ uint vals[SORT_CAP];
  __shared__ int cnt[128], pre[128], cur[128];
  const int t = threadIdx.x;
  const int b = blockIdx.x;
  const int e0 = boffs[b];
  const int e1 = boffs[b + 1];
  const int n = e1 - e0;

  if (t < 128) cnt[t] = 0;
  __syncthreads();
  for (int i = t; i < n; i += 256) {
    uint v = ebuf[e0 + i];
    vals[i] = v;
    atomicAdd(&cnt[v >> 17], 1);
  }
  __syncthreads();

  // exclusive scan of 128 counters
  if (t < 128) pre[t] = cnt[t];
  __syncthreads();
  for (int off = 1; off < 128; off <<= 1) {
    int y = (t < 128 && t >= off) ? pre[t - off] : 0;
    __syncthreads();
    if (t < 128) pre[t] += y;
    __syncthreads();
  }
  if (t < 128) {
    const int excl = pre[t] - cnt[t];
    cur[t] = excl;
    const int nid = b * 128 + t;
    if (nid < NN) {
      offs[nid] = e0 + excl;
      dinv[nid] = rsqrtf((float)cnt[t] + 1.0f);   // +1 self loop
    } else if (nid == NN) {
      offs[NN] = e0 + excl;                       // == NE
    }
  }
  __syncthreads();

  // scatter back in place, sorted by local dst, payload = plain src
  for (int i = t; i < n; i += 256) {
    const uint v = vals[i];
    const int r = atomicAdd(&cur[v >> 17], 1);
    ebuf[e0 + r] = v & 0x1FFFFu;
  }
}

// ---------------- weight pack (fragment layout) ----------------
__global__ void k_pack(const float* __restrict__ W, ushort* __restrict__ Wp, int K, int Nw) {
  int t = blockIdx.x * 256 + threadIdx.x;
  int total = (K / 32) * (Nw / 16) * 64;
  if (t >= total) return;
  int l  = t & 63;
  int nf = (t >> 6) % (Nw / 16);
  int ks = (t >> 6) / (Nw / 16);
  int krow = ks * 32 + (l >> 4) * 8;
  int col  = nf * 16 + (l & 15);
  ushort out[8];
#pragma unroll
  for (int j = 0; j < 8; ++j) out[j] = f2bf(W[(size_t)(krow + j) * Nw + col]);
  *(uint4*)&Wp[(size_t)t * 8] = *(const uint4*)out;
}

// ---------------- GEMM: C[M,NW] = bf16( (bnrelu(A[M,K]) @ W) * dinv[row] ) ----------------
template <int K, int NW, bool BN>
__launch_bounds__(256)
__global__ void k_gemm(const float* __restrict__ A, const ushort* __restrict__ Wp,
                       const float* __restrict__ scale, const float* __restrict__ shift,
                       const float* __restrict__ dinv, ushort* __restrict__ Cout, int M) {
  constexpr int LDA = 40;
  __shared__ ushort lds[128 * LDA];
  const int t = threadIdx.x;
  const int lane = t & 63;
  const int wid = t >> 6;
  const int m0 = blockIdx.x * 128;

  constexpr int WAVES_N = (NW == 128) ? 2 : 1;
  constexpr int MF  = (NW == 128) ? 4 : 2;
  constexpr int NFW = 4;
  constexpr int NFT = NW / 16;
  const int wr = wid / WAVES_N;
  const int wc = wid % WAVES_N;
  const int mbase = wr * (MF * 16);
  const int nfg0 = wc * NFW;

  f32x4 acc[MF][NFW] = {};

  const int cg = t & 7;
  const int r0 = t >> 3;

  const int nkt = K / 32;
  for (int kt = 0; kt < nkt; ++kt) {
    const int k0 = kt * 32;
    float4 s4 = {1.f, 1.f, 1.f, 1.f}, h4 = {0.f, 0.f, 0.f, 0.f};
    if (BN) {
      s4 = *(const float4*)&scale[k0 + cg * 4];
      h4 = *(const float4*)&shift[k0 + cg * 4];
    }
    __syncthreads();
#pragma unroll
    for (int p = 0; p < 4; ++p) {
      const int row = p * 32 + r0;
      const int grow = m0 + row;
      float4 v = {0.f, 0.f, 0.f, 0.f};
      if (grow < M) v = *(const float4*)&A[(size_t)grow * K + k0 + cg * 4];
      if (BN) {
        v.x = fmaxf(v.x * s4.x + h4.x, 0.f);
        v.y = fmaxf(v.y * s4.y + h4.y, 0.f);
        v.z = fmaxf(v.z * s4.z + h4.z, 0.f);
        v.w = fmaxf(v.w * s4.w + h4.w, 0.f);
      }
      ushort4 w;
      w.x = f2bf(v.x); w.y = f2bf(v.y); w.z = f2bf(v.z); w.w = f2bf(v.w);
      *(ushort4*)&lds[row * LDA + cg * 4] = w;
    }
    __syncthreads();

    short8 bfrag[NFW];
#pragma unroll
    for (int nf = 0; nf < NFW; ++nf) {
      const size_t bidx = ((size_t)(kt * NFT + nfg0 + nf) * 64 + lane) * 8;
      bfrag[nf] = *(const short8*)&Wp[bidx];
    }
#pragma unroll
    for (int mf = 0; mf < MF; ++mf) {
      const short8 af =
          *(const short8*)&lds[(mbase + mf * 16 + (lane & 15)) * LDA + ((lane >> 4) * 8)];
#pragma unroll
      for (int nf = 0; nf < NFW; ++nf)
        acc[mf][nf] = __builtin_amdgcn_mfma_f32_16x16x32_bf16(af, bfrag[nf], acc[mf][nf], 0, 0, 0);
    }
  }

#pragma unroll
  for (int mf = 0; mf < MF; ++mf) {
#pragma unroll
    for (int r = 0; r < 4; ++r) {
      const int grow = m0 + mbase + mf * 16 + (lane >> 4) * 4 + r;
      if (grow < M) {
        const float dv = dinv[grow];
#pragma unroll
        for (int nf = 0; nf < NFW; ++nf) {
          const int gcol = (nfg0 + nf) * 16 + (lane & 15);
          Cout[(size_t)grow * NW + gcol] = f2bf(acc[mf][nf][r] * dv);
        }
      }
    }
  }
}

// ---------------- pull-propagate (wave per node, scalarized indices) ----------------
// G pre-scaled by dinv[src].  H[d] = dinv[d]*( sum_{s->d} G'[s] + G'[d] ) + b
// nid is readfirstlane'd so offs/dinv/csr loads become scalar (s_load) and the
// edge loop bounds are SGPR; csr tail reads are unconditional (clamped) so the
// 8 index loads batch into s_load_dwordx8.
__launch_bounds__(256)
__global__ void k_prop128(const ushort* __restrict__ G, const int* __restrict__ offs,
                          const int* __restrict__ csr, const float* __restrict__ dinv,
                          const float* __restrict__ bias, float* __restrict__ H, int n) {
  const int wid = threadIdx.x >> 6;
  const int lane = threadIdx.x & 63;
  const int nid = __builtin_amdgcn_readfirstlane(blockIdx.x * 4 + wid);
  if (nid >= n) return;
  const int d0 = lane * 2;
  ushort2 gs = *(const ushort2*)(G + (size_t)nid * 128 + d0);
  float a0 = bf2f(gs.x);   // self term (already * dinv)
  float a1 = bf2f(gs.y);
  const int e0 = offs[nid];        // scalar loads (nid uniform)
  const int e1 = offs[nid + 1];
  for (int e = e0; e < e1; e += 8) {
    int idx[8];
#pragma unroll
    for (int i = 0; i < 8; ++i) idx[i] = csr[e + i] & 0x1FFFF;  // s_load batch; clamp tail garbage
    ushort2 g[8];
#pragma unroll
    for (int i = 0; i < 8; ++i) g[i] = *(const ushort2*)(G + (size_t)idx[i] * 128 + d0);
#pragma unroll
    for (int i = 0; i < 8; ++i) {
      if (e + i < e1) {   // uniform predicate
        a0 += bf2f(g[i].x);
        a1 += bf2f(g[i].y);
      }
    }
  }
  const float di = dinv[nid];      // scalar load
  const float2 b2 = *(const float2*)&bias[d0];
  float2 o;
  o.x = a0 * di + b2.x;
  o.y = a1 * di + b2.y;
  *(float2*)&H[(size_t)nid * 128 + d0] = o;
}

__launch_bounds__(256)
__global__ void k_prop64(const ushort* __restrict__ G, const int* __restrict__ offs,
                         const int* __restrict__ csr, const float* __restrict__ dinv,
                         const float* __restrict__ bias, float* __restrict__ out, int n) {
  const int wid = threadIdx.x >> 6;
  const int lane = threadIdx.x & 63;
  const int nid = __builtin_amdgcn_readfirstlane(blockIdx.x * 4 + wid);
  if (nid >= n) return;
  float a = bf2f(G[(size_t)nid * 64 + lane]);   // self term
  const int e0 = offs[nid];
  const int e1 = offs[nid + 1];
  for (int e = e0; e < e1; e += 8) {
    int idx[8];
#pragma unroll
    for (int i = 0; i < 8; ++i) idx[i] = csr[e + i] & 0x1FFFF;
    ushort g[8];
#pragma unroll
    for (int i = 0; i < 8; ++i) g[i] = G[(size_t)idx[i] * 64 + lane];
#pragma unroll
    for (int i = 0; i < 8; ++i)
      if (e + i < e1) a += bf2f(g[i]);
  }
  out[(size_t)nid * 64 + lane] = a * dinv[nid] + bias[lane];
}

// ---------------- BN stats ----------------
__launch_bounds__(256)
__global__ void k_stats(const float* __restrict__ H, float* __restrict__ sum,
                        float* __restrict__ sumsq, int n) {
  const int d = threadIdx.x & 127;
  const int half = threadIdx.x >> 7;
  const int rpb = (n + gridDim.x - 1) / gridDim.x;
  const int r0 = blockIdx.x * rpb;
  const int r1 = min(n, r0 + rpb);
  float s = 0.f, q = 0.f;
  for (int r = r0 + half; r < r1; r += 2) {
    const float v = H[(size_t)r * 128 + d];
    s += v;
    q += v * v;
  }
  __shared__ float ls[256], lq[256];
  ls[threadIdx.x] = s;
  lq[threadIdx.x] = q;
  __syncthreads();
  if (half == 0) {
    atomicAdd(&sum[d], s + ls[d + 128]);
    atomicAdd(&sumsq[d], q + lq[d + 128]);
  }
}

__global__ void k_finalize(const float* __restrict__ sum, const float* __restrict__ sumsq,
                           const float* __restrict__ g, const float* __restrict__ bt,
                           float* __restrict__ scale, float* __restrict__ shift) {
  const int d = threadIdx.x;
  const float inv_n = 1.0f / (float)NN;
  const float mu = sum[d] * inv_n;
  float var = sumsq[d] * inv_n - mu * mu;
  const float rs = rsqrtf(var + BN_EPS);
  const float sc = g[d] * rs;
  scale[d] = sc;
  shift[d] = bt[d] - mu * sc;
}

// ---------------- launch ----------------
extern "C" void kernel_launch(void* const* d_in, const int* in_sizes, int n_in,
                              void* d_out, int out_size, void* d_ws, size_t ws_size,
                              hipStream_t stream) {
  const float* x   = (const float*)d_in[0];
  const int*  ei   = (const int*)d_in[1];
  const int*  srcp = ei;
  const int*  dstp = ei + NE;
  const float* W1  = (const float*)d_in[2];
  const float* b1  = (const float*)d_in[3];
  const float* g1  = (const float*)d_in[4];
  const float* bt1 = (const float*)d_in[5];
  const float* W2  = (const float*)d_in[6];
  const float* b2  = (const float*)d_in[7];
  const float* g2  = (const float*)d_in[8];
  const float* bt2 = (const float*)d_in[9];
  const float* W3  = (const float*)d_in[10];
  const float* b3  = (const float*)d_in[11];
  float* out = (float*)d_out;

  char* p = (char*)d_ws;
  auto alloc = [&](size_t bytes) {
    char* r = p;
    p += (bytes + 255) & ~(size_t)255;
    return r;
  };
  int*    bcnt    = (int*)alloc(NBUCK * 4);
  int*    boffs   = (int*)alloc((NBUCK + 1) * 4);
  int*    gcursor = (int*)alloc(NBUCK * 4);
  uint*   ebuf    = (uint*)alloc((size_t)NE * 4);   // packed, then sorted plain-src
  int*    offs    = (int*)alloc((NN + 1) * 4);
  float*  dinv    = (float*)alloc(NN * 4);
  float*  gsum    = (float*)alloc(DH * 4);
  float*  gsumsq  = (float*)alloc(DH * 4);
  float*  scale   = (float*)alloc(DH * 4);
  float*  shift   = (float*)alloc(DH * 4);
  ushort* Wp1     = (ushort*)alloc((size_t)DIN * DH * 2);
  ushort* Wp2     = (ushort*)alloc((size_t)DH * DH * 2);
  ushort* Wp3     = (ushort*)alloc((size_t)DH * DOUT * 2);
  ushort* G       = (ushort*)alloc((size_t)NN * DH * 2);
  float*  H       = (float*)alloc((size_t)NN * DH * 4);

  const int GB = (NN + 127) / 128;   // 782 gemm blocks
  const int PB = (NN + 3) / 4;       // 25000 prop blocks

  // bucket-CSR build + per-bucket sort -> per-node CSR
  hipMemsetAsync(bcnt, 0, NBUCK * 4, stream);
  k_bhist<<<(NE + 4095) / 4096, 256, 0, stream>>>(dstp, bcnt);
  k_bscan<<<1, 1024, 0, stream>>>(bcnt, boffs, gcursor);
  k_bfill<<<NBF, 256, 0, stream>>>(srcp, dstp, gcursor, ebuf);
  k_sort<<<NBUCK, 256, 0, stream>>>(ebuf, boffs, offs, dinv);
  const int* csr = (const int*)ebuf;

  // weight packing
  k_pack<<<16, 256, 0, stream>>>(W1, Wp1, DIN, DH);
  k_pack<<<8, 256, 0, stream>>>(W2, Wp2, DH, DH);
  k_pack<<<4, 256, 0, stream>>>(W3, Wp3, DH, DOUT);

  // layer 1
  k_gemm<DIN, DH, false><<<GB, 256, 0, stream>>>(x, Wp1, nullptr, nullptr, dinv, G, NN);
  k_prop128<<<PB, 256, 0, stream>>>(G, offs, csr, dinv, b1, H, NN);
  hipMemsetAsync(gsum, 0, DH * 4, stream);
  hipMemsetAsync(gsumsq, 0, DH * 4, stream);
  k_stats<<<512, 256, 0, stream>>>(H, gsum, gsumsq, NN);
  k_finalize<<<1, DH, 0, stream>>>(gsum, gsumsq, g1, bt1, scale, shift);

  // layer 2
  k_gemm<DH, DH, true><<<GB, 256, 0, stream>>>(H, Wp2, scale, shift, dinv, G, NN);
  k_prop128<<<PB, 256, 0, stream>>>(G, offs, csr, dinv, b2, H, NN);
  hipMemsetAsync(gsum, 0, DH * 4, stream);
  hipMemsetAsync(gsumsq, 0, DH * 4, stream);
  k_stats<<<512, 256, 0, stream>>>(H, gsum, gsumsq, NN);
  k_finalize<<<1, DH, 0, stream>>>(gsum, gsumsq, g2, bt2, scale, shift);

  // layer 3
  k_gemm<DH, DOUT, true><<<GB, 256, 0, stream>>>(H, Wp3, scale, shift, dinv, G, NN);
  k_prop64<<<PB, 256, 0, stream>>>(G, offs, csr, dinv, b3, out, NN);
}